// Round 1
// baseline (881.454 us; speedup 1.0000x reference)
//
#include <hip/hip_runtime.h>
#include <math.h>

// Workspace layout (floats):
//   G    [4][64][64] @ 0      (16384)  -- raw Gram sums, atomically accumulated
//   Sc   [4][64]     @ 16384  (256)    -- channel sums of cF
//   Ss   [4][64]     @ 16640  (256)    -- channel sums of sF
//   T    [4][64][64] @ 16896  (16384)  -- fused transform alpha*CM*F + (1-a)I
//   bias [4][64]     @ 33280  (256)
#define WS_G 0
#define WS_SC 16384
#define WS_SS 16640
#define WS_T 16896
#define WS_BIAS 33280
#define WS_ZERO_COUNT 16896

__device__ __forceinline__ float waveRed(float v) {
#pragma unroll
    for (int o = 32; o > 0; o >>= 1) v += __shfl_down(v, o, 64);
    return v;
}

__global__ void zero_kernel(float* __restrict__ ws, int n) {
    int i = blockIdx.x * 256 + threadIdx.x;
    if (i < n) ws[i] = 0.f;
}

// Per-channel sums of x ([256 channels][N]); 8 blocks per channel.
__global__ __launch_bounds__(256) void sum_kernel(const float* __restrict__ x,
                                                  float* __restrict__ sums, int N) {
    const int ch = blockIdx.x >> 3;
    const int part = blockIdx.x & 7;
    const int seg = N >> 3;
    const float4* p = reinterpret_cast<const float4*>(x + (size_t)ch * N + (size_t)part * seg);
    const int nf4 = seg >> 2;
    float acc = 0.f;
    for (int i = threadIdx.x; i < nf4; i += 256) {
        float4 v = p[i];
        acc += (v.x + v.y) + (v.z + v.w);
    }
    acc = waveRed(acc);
    __shared__ float red[4];
    if ((threadIdx.x & 63) == 0) red[threadIdx.x >> 6] = acc;
    __syncthreads();
    if (threadIdx.x == 0) atomicAdd(&sums[ch], (red[0] + red[1]) + (red[2] + red[3]));
}

// Gram kernel: G[b] += cf_chunk * cf_chunk^T, plus channel sums of cF.
// tile stride 129: bank = (r + x) % 32 -> scalar reads are conflict-free.
#define GSTR 129
__global__ __launch_bounds__(256) void gram_kernel(const float* __restrict__ cF,
                                                   float* __restrict__ G,
                                                   float* __restrict__ Sc, int N) {
    __shared__ float tile[64 * GSTR];
    const int b = blockIdx.x >> 7;
    const int part = blockIdx.x & 127;
    const float* base = cF + (size_t)b * 64 * N + (size_t)part * (N >> 7);
    const int t = threadIdx.x;
    const int c0 = (t >> 4) << 2;
    const int d0 = (t & 15) << 2;
    float acc[4][4];
#pragma unroll
    for (int i = 0; i < 4; ++i)
#pragma unroll
        for (int j = 0; j < 4; ++j) acc[i][j] = 0.f;
    float rowsum = 0.f;
    for (int sub = 0; sub < 16; ++sub) {
        const float* gsrc = base + sub * 128;
#pragma unroll
        for (int i = 0; i < 8; ++i) {
            int f = t + 256 * i;
            int row = f >> 5, col4 = f & 31;
            float4 v = *reinterpret_cast<const float4*>(gsrc + (size_t)row * N + col4 * 4);
            float* d = &tile[row * GSTR + col4 * 4];
            d[0] = v.x; d[1] = v.y; d[2] = v.z; d[3] = v.w;
        }
        __syncthreads();
        if (t < 64) {
            const float* tr = &tile[t * GSTR];
#pragma unroll 8
            for (int x = 0; x < 128; ++x) rowsum += tr[x];
        }
        const float* ta = &tile[c0 * GSTR];
        const float* tb = &tile[d0 * GSTR];
#pragma unroll 4
        for (int x = 0; x < 128; ++x) {
            float a0 = ta[0 * GSTR + x], a1 = ta[1 * GSTR + x];
            float a2 = ta[2 * GSTR + x], a3 = ta[3 * GSTR + x];
            float b0 = tb[0 * GSTR + x], b1 = tb[1 * GSTR + x];
            float b2 = tb[2 * GSTR + x], b3 = tb[3 * GSTR + x];
            acc[0][0] += a0 * b0; acc[0][1] += a0 * b1; acc[0][2] += a0 * b2; acc[0][3] += a0 * b3;
            acc[1][0] += a1 * b0; acc[1][1] += a1 * b1; acc[1][2] += a1 * b2; acc[1][3] += a1 * b3;
            acc[2][0] += a2 * b0; acc[2][1] += a2 * b1; acc[2][2] += a2 * b2; acc[2][3] += a2 * b3;
            acc[3][0] += a3 * b0; acc[3][1] += a3 * b1; acc[3][2] += a3 * b2; acc[3][3] += a3 * b3;
        }
        __syncthreads();
    }
    float* Gb = G + b * 4096;
#pragma unroll
    for (int i = 0; i < 4; ++i)
#pragma unroll
        for (int j = 0; j < 4; ++j) atomicAdd(&Gb[(c0 + i) * 64 + d0 + j], acc[i][j]);
    if (t < 64) atomicAdd(&Sc[b * 64 + t], rowsum);
}

// ---------- solver: cov -> Newton-Schulz inverse sqrt -> fused transform ----------
#define SSTR 68  // multiple of 4 => float4-aligned rows; bank = (4r + c) % 32

__device__ __forceinline__ void matmul44(float* __restrict__ D, const float* __restrict__ A,
                                         const float* __restrict__ Bm, int i0, int j0) {
    // D[i0..+3][j0..+3] = sum_k A[i][k] * B[k][j]; D must not alias A or Bm.
    float acc[4][4];
#pragma unroll
    for (int i = 0; i < 4; ++i)
#pragma unroll
        for (int j = 0; j < 4; ++j) acc[i][j] = 0.f;
    for (int k = 0; k < 64; ++k) {
        float4 bv = *reinterpret_cast<const float4*>(&Bm[k * SSTR + j0]);
        float a0 = A[(i0 + 0) * SSTR + k];
        float a1 = A[(i0 + 1) * SSTR + k];
        float a2 = A[(i0 + 2) * SSTR + k];
        float a3 = A[(i0 + 3) * SSTR + k];
        acc[0][0] += a0 * bv.x; acc[0][1] += a0 * bv.y; acc[0][2] += a0 * bv.z; acc[0][3] += a0 * bv.w;
        acc[1][0] += a1 * bv.x; acc[1][1] += a1 * bv.y; acc[1][2] += a1 * bv.z; acc[1][3] += a1 * bv.w;
        acc[2][0] += a2 * bv.x; acc[2][1] += a2 * bv.y; acc[2][2] += a2 * bv.z; acc[2][3] += a2 * bv.w;
        acc[3][0] += a3 * bv.x; acc[3][1] += a3 * bv.y; acc[3][2] += a3 * bv.z; acc[3][3] += a3 * bv.w;
    }
#pragma unroll
    for (int i = 0; i < 4; ++i)
#pragma unroll
        for (int j = 0; j < 4; ++j) D[(i0 + i) * SSTR + j0 + j] = acc[i][j];
}

__global__ __launch_bounds__(256) void solve_kernel(const float* __restrict__ G,
                                                    const float* __restrict__ Sc,
                                                    const float* __restrict__ Ss,
                                                    const float* __restrict__ alphap,
                                                    const float* __restrict__ s_e,
                                                    const float* __restrict__ s_v,
                                                    float* __restrict__ Tg,
                                                    float* __restrict__ biasg, int N) {
    __shared__ __align__(16) float Abuf[64 * SSTR];
    __shared__ __align__(16) float Ybuf[64 * SSTR];
    __shared__ __align__(16) float Tbuf[64 * SSTR];
    __shared__ __align__(16) float Wb[64 * 20];
    __shared__ float sdv[64], mcv[64], msv[64];
    __shared__ float redv;
    const int b = blockIdx.x, t = threadIdx.x;
    const int i0 = (t >> 4) << 2, j0 = (t & 15) << 2;
    const float invN = 1.f / (float)N;
    const float invNm1 = 1.f / (float)(N - 1);
    if (t < 64) {
        mcv[t] = Sc[b * 64 + t] * invN;
        msv[t] = Ss[b * 64 + t] * invN;
        sdv[t] = sqrtf(s_e[b * 64 + t]);
    }
    __syncthreads();
    // cov = (G - N*mu*mu^T)/(N-1) + I
#pragma unroll
    for (int i = 0; i < 4; ++i) {
        float mi = mcv[i0 + i];
#pragma unroll
        for (int j = 0; j < 4; ++j) {
            float g = G[b * 4096 + (i0 + i) * 64 + j0 + j];
            float cov = (g - mi * mcv[j0 + j] * (float)N) * invNm1 + (((i0 + i) == (j0 + j)) ? 1.f : 0.f);
            Abuf[(i0 + i) * SSTR + j0 + j] = cov;
        }
    }
    __syncthreads();
    if (t < 64) {
        float d = waveRed(Abuf[t * SSTR + t]);
        if (t == 0) redv = d * (1.f / 64.f);
    }
    __syncthreads();
    const float s = redv;
    const float inv_s = 1.f / s;
#pragma unroll
    for (int i = 0; i < 4; ++i)
#pragma unroll
        for (int j = 0; j < 4; ++j) {
            Abuf[(i0 + i) * SSTR + j0 + j] *= inv_s;  // A = cov/s, eigs ~ 1 +- 0.02
            Ybuf[(i0 + i) * SSTR + j0 + j] = ((i0 + i) == (j0 + j)) ? 1.f : 0.f;
        }
    __syncthreads();
    // Newton-Schulz: Y <- 0.5 * Y * (3I - A*Y*Y); 3 iters => fp32-exact (||I-A||~0.016)
    const int kr = t >> 2;         // 0..63
    const int cw = (t & 3) << 2;   // 0,4,8,12
    for (int it = 0; it < 3; ++it) {
        matmul44(Tbuf, Ybuf, Ybuf, i0, j0);  // Tbuf = Y*Y
        __syncthreads();
        for (int lb = 0; lb < 4; ++lb) {
            const int cb = lb << 4;
            float w0 = 0.f, w1 = 0.f, w2 = 0.f, w3 = 0.f;
            for (int j = 0; j < 64; ++j) {
                float a = Abuf[kr * SSTR + j];
                float4 tv = *reinterpret_cast<const float4*>(&Tbuf[j * SSTR + cb + cw]);
                w0 += a * tv.x; w1 += a * tv.y; w2 += a * tv.z; w3 += a * tv.w;
            }
            Wb[kr * 20 + cw + 0] = ((kr == cb + cw + 0) ? 1.5f : 0.f) - 0.5f * w0;
            Wb[kr * 20 + cw + 1] = ((kr == cb + cw + 1) ? 1.5f : 0.f) - 0.5f * w1;
            Wb[kr * 20 + cw + 2] = ((kr == cb + cw + 2) ? 1.5f : 0.f) - 0.5f * w2;
            Wb[kr * 20 + cw + 3] = ((kr == cb + cw + 3) ? 1.5f : 0.f) - 0.5f * w3;
            __syncthreads();
            float y0 = 0.f, y1 = 0.f, y2 = 0.f, y3 = 0.f;
            for (int k = 0; k < 64; ++k) {
                float a = Ybuf[kr * SSTR + k];
                float4 wv = *reinterpret_cast<const float4*>(&Wb[k * 20 + cw]);
                y0 += a * wv.x; y1 += a * wv.y; y2 += a * wv.z; y3 += a * wv.w;
            }
            Tbuf[kr * SSTR + cb + cw + 0] = y0;
            Tbuf[kr * SSTR + cb + cw + 1] = y1;
            Tbuf[kr * SSTR + cb + cw + 2] = y2;
            Tbuf[kr * SSTR + cb + cw + 3] = y3;
            __syncthreads();
        }
#pragma unroll
        for (int i = 0; i < 4; ++i)
#pragma unroll
            for (int j = 0; j < 4; ++j)
                Ybuf[(i0 + i) * SSTR + j0 + j] = Tbuf[(i0 + i) * SSTR + j0 + j];
        __syncthreads();
    }
    // Ybuf ~ (cov/s)^{-1/2}; F = Ybuf / sqrt(s)
    // colorM = s_v * diag(sqrt(s_e)) * s_v^T  (into Tbuf, s_v staged in Abuf)
    for (int i = 0; i < 16; ++i) {
        int idx = t + 256 * i;
        Abuf[(idx >> 6) * SSTR + (idx & 63)] = s_v[b * 4096 + idx];
    }
    __syncthreads();
    {
        float acc[4][4];
#pragma unroll
        for (int i = 0; i < 4; ++i)
#pragma unroll
            for (int j = 0; j < 4; ++j) acc[i][j] = 0.f;
        for (int k = 0; k < 64; ++k) {
            float sd = sdv[k];
            float a0 = Abuf[(i0 + 0) * SSTR + k] * sd;
            float a1 = Abuf[(i0 + 1) * SSTR + k] * sd;
            float a2 = Abuf[(i0 + 2) * SSTR + k] * sd;
            float a3 = Abuf[(i0 + 3) * SSTR + k] * sd;
            float c0v = Abuf[(j0 + 0) * SSTR + k];
            float c1v = Abuf[(j0 + 1) * SSTR + k];
            float c2v = Abuf[(j0 + 2) * SSTR + k];
            float c3v = Abuf[(j0 + 3) * SSTR + k];
            acc[0][0] += a0 * c0v; acc[0][1] += a0 * c1v; acc[0][2] += a0 * c2v; acc[0][3] += a0 * c3v;
            acc[1][0] += a1 * c0v; acc[1][1] += a1 * c1v; acc[1][2] += a1 * c2v; acc[1][3] += a1 * c3v;
            acc[2][0] += a2 * c0v; acc[2][1] += a2 * c1v; acc[2][2] += a2 * c2v; acc[2][3] += a2 * c3v;
            acc[3][0] += a3 * c0v; acc[3][1] += a3 * c1v; acc[3][2] += a3 * c2v; acc[3][3] += a3 * c3v;
        }
        __syncthreads();
#pragma unroll
        for (int i = 0; i < 4; ++i)
#pragma unroll
            for (int j = 0; j < 4; ++j) Tbuf[(i0 + i) * SSTR + j0 + j] = acc[i][j];
    }
    __syncthreads();
    matmul44(Abuf, Tbuf, Ybuf, i0, j0);  // Abuf = colorM * Y  (scale below)
    __syncthreads();
    const float alpha_v = alphap[0];
    const float fac = alpha_v / sqrtf(s);  // alpha / sqrt(s): M2 = fac * Abuf
#pragma unroll
    for (int i = 0; i < 4; ++i)
#pragma unroll
        for (int j = 0; j < 4; ++j) {
            float m = Abuf[(i0 + i) * SSTR + j0 + j] * fac;
            if ((i0 + i) == (j0 + j)) m += 1.f - alpha_v;
            Tg[b * 4096 + (i0 + i) * 64 + j0 + j] = m;
        }
    if (t < 64) {
        float acc = 0.f;
        for (int d = 0; d < 64; ++d) acc += Abuf[t * SSTR + d] * mcv[d];
        biasg[b * 64 + t] = alpha_v * msv[t] - fac * acc;
    }
}

// Apply: out[c][x] = sum_k T[c][k]*cf[k][x] + bias[c]
// tile stride 132 (multiple of 4): float4 reads at fixed row k across lanes are conflict-free.
#define ASTR 132
__global__ __launch_bounds__(256) void apply_kernel(const float* __restrict__ cF,
                                                    const float* __restrict__ T,
                                                    const float* __restrict__ bias,
                                                    float* __restrict__ out, int N) {
    __shared__ __align__(16) float tile[64 * ASTR];
    __shared__ float Tl[64 * 65];
    __shared__ float bl[64];
    const int b = blockIdx.x >> 9;
    const int part = blockIdx.x & 511;
    const int chunk = N >> 9;  // 512
    const float* src = cF + (size_t)b * 64 * N + (size_t)part * chunk;
    float* dst = out + (size_t)b * 64 * N + (size_t)part * chunk;
    const int t = threadIdx.x;
    for (int i = 0; i < 16; ++i) {
        int idx = t + 256 * i;
        Tl[(idx >> 6) * 65 + (idx & 63)] = T[b * 4096 + idx];
    }
    if (t < 64) bl[t] = bias[b * 64 + t];
    const int x0 = (t & 7) * 4;
    const int cA = (t >> 3) * 2;
    for (int sub = 0; sub < 4; ++sub) {
        __syncthreads();  // Tl ready / previous compute done
        const float* gsrc = src + sub * 128;
#pragma unroll
        for (int i = 0; i < 8; ++i) {
            int f = t + 256 * i;
            int row = f >> 5, col4 = f & 31;
            *reinterpret_cast<float4*>(&tile[row * ASTR + col4 * 4]) =
                *reinterpret_cast<const float4*>(gsrc + (size_t)row * N + col4 * 4);
        }
        __syncthreads();
        float b0 = bl[cA], b1 = bl[cA + 1];
        float4 acc0[4], acc1[4];
#pragma unroll
        for (int g = 0; g < 4; ++g) {
            acc0[g] = make_float4(b0, b0, b0, b0);
            acc1[g] = make_float4(b1, b1, b1, b1);
        }
        const float* t0 = &Tl[cA * 65];
        const float* t1 = &Tl[(cA + 1) * 65];
#pragma unroll 2
        for (int k = 0; k < 64; ++k) {
            float a0 = t0[k], a1 = t1[k];
            const float* trow = &tile[k * ASTR + x0];
#pragma unroll
            for (int g = 0; g < 4; ++g) {
                float4 v = *reinterpret_cast<const float4*>(trow + 32 * g);
                acc0[g].x += a0 * v.x; acc0[g].y += a0 * v.y; acc0[g].z += a0 * v.z; acc0[g].w += a0 * v.w;
                acc1[g].x += a1 * v.x; acc1[g].y += a1 * v.y; acc1[g].z += a1 * v.z; acc1[g].w += a1 * v.w;
            }
        }
        float* d0 = dst + (size_t)cA * N + sub * 128 + x0;
        float* d1 = dst + (size_t)(cA + 1) * N + sub * 128 + x0;
#pragma unroll
        for (int g = 0; g < 4; ++g) {
            *reinterpret_cast<float4*>(d0 + 32 * g) = acc0[g];
            *reinterpret_cast<float4*>(d1 + 32 * g) = acc1[g];
        }
    }
}

extern "C" void kernel_launch(void* const* d_in, const int* in_sizes, int n_in,
                              void* d_out, int out_size, void* d_ws, size_t ws_size,
                              hipStream_t stream) {
    const float* cF = (const float*)d_in[0];
    const float* sF = (const float*)d_in[1];
    const float* alpha = (const float*)d_in[2];
    const float* s_e = (const float*)d_in[3];
    const float* s_v = (const float*)d_in[4];
    float* out = (float*)d_out;
    float* ws = (float*)d_ws;
    const int B = 4, C = 64;
    const int N = in_sizes[0] / (B * C);  // 262144
    float* G = ws + WS_G;
    float* Sc = ws + WS_SC;
    float* Ss = ws + WS_SS;
    float* T = ws + WS_T;
    float* bias = ws + WS_BIAS;
    hipLaunchKernelGGL(zero_kernel, dim3(66), dim3(256), 0, stream, ws, WS_ZERO_COUNT);
    hipLaunchKernelGGL(sum_kernel, dim3(B * C * 8), dim3(256), 0, stream, sF, Ss, N);
    hipLaunchKernelGGL(gram_kernel, dim3(B * 128), dim3(256), 0, stream, cF, G, Sc, N);
    hipLaunchKernelGGL(solve_kernel, dim3(B), dim3(256), 0, stream, G, Sc, Ss, alpha, s_e, s_v, T, bias, N);
    hipLaunchKernelGGL(apply_kernel, dim3(B * 512), dim3(256), 0, stream, cF, T, bias, out, N);
}